// Round 3
// baseline (229.050 us; speedup 1.0000x reference)
//
#include <hip/hip_runtime.h>
#include <hip/hip_bf16.h>

#define N_ROWS 131072
#define K_MIX  256
#define D_DIM  128
#define LDSB_STRIDE 136            // shorts per B row: 128 + 8 pad (rows 272 B, 16B aligned)
#define B_CHUNKS (K_MIX * LDSB_STRIDE / 8)   // 4352 bf16x8 chunks = 69632 B

typedef float  f32x4  __attribute__((ext_vector_type(4)));
typedef short  bf16x8 __attribute__((ext_vector_type(8)));

__device__ inline bf16x8 pack8(float4 a, float4 b) {
    union { bf16x8 v; __hip_bfloat162 h[4]; } u;
    u.h[0] = __float22bfloat162_rn(make_float2(a.x, a.y));
    u.h[1] = __float22bfloat162_rn(make_float2(a.z, a.w));
    u.h[2] = __float22bfloat162_rn(make_float2(b.x, b.y));
    u.h[3] = __float22bfloat162_rn(make_float2(b.z, b.w));
    return u.v;
}

// ---------------- prep: ws <- padded bf16(prec*mu), fp32 0.5*musq ----------------
__global__ void prep_kernel(const float* __restrict__ mu,
                            const float* __restrict__ prec,
                            unsigned short* __restrict__ Bp,
                            float* __restrict__ musq)
{
    int idx = blockIdx.x * 256 + threadIdx.x;   // 0..8191 float4s of mu
    int row = idx >> 5;                          // mixture component k
    int c4  = idx & 31;                          // float4 within row
    float4 mv = ((const float4*)mu)[idx];
    float4 pv = ((const float4*)prec)[c4];
    float px = mv.x * pv.x, py = mv.y * pv.y, pz = mv.z * pv.z, pw = mv.w * pv.w;
    union { ushort4 u4; __hip_bfloat162 h[2]; } h;
    h.h[0] = __float22bfloat162_rn(make_float2(px, py));
    h.h[1] = __float22bfloat162_rn(make_float2(pz, pw));
    *(ushort4*)&Bp[row * LDSB_STRIDE + c4 * 4] = h.u4;
    if (c4 == 31) {     // zero the 8-short pad
        bf16x8 z = (bf16x8)0;
        *(bf16x8*)&Bp[row * LDSB_STRIDE + 128] = z;
    }
    float ps = px * mv.x + py * mv.y + pz * mv.z + pw * mv.w;
    ps += __shfl_xor(ps, 1);  ps += __shfl_xor(ps, 2);
    ps += __shfl_xor(ps, 4);  ps += __shfl_xor(ps, 8);
    ps += __shfl_xor(ps, 16);
    if ((threadIdx.x & 31) == 0) musq[row] = 0.5f * ps;   // pre-scaled
}

// ---------------- main ----------------
__global__ __launch_bounds__(256, 2)
void mixture_main(const float* __restrict__ x,
                  const unsigned short* __restrict__ Bp,
                  const float* __restrict__ musqg,
                  const float* __restrict__ prec,
                  float* __restrict__ out)
{
    __shared__ __align__(16) unsigned short sB[K_MIX * LDSB_STRIDE];
    __shared__ float sMusq[K_MIX];      // holds -0.5*musq (acc-init ready)
    __shared__ float sPrec[D_DIM];
    __shared__ float sRed[4];

    const int tid  = threadIdx.x;
    const int lane = tid & 63;
    const int wave = tid >> 6;
    const int low4 = lane & 15;
    const int q    = lane >> 4;

    const float4* x4 = (const float4*)x;

    // row bases for this wave's two rowgroups
    const int rbase0 = blockIdx.x * 256 + wave * 32;
    const float4* xr0_g0 = x4 + (size_t)(rbase0 + low4) * 32;
    const float4* xr1_g0 = x4 + (size_t)(rbase0 + low4 + 16) * 32;
    const float4* xr0_g1 = xr0_g0 + 128 * 32;
    const float4* xr1_g1 = xr1_g0 + 128 * 32;

    // ---- issue rg0 k0 x-prefetch BEFORE the staging barrier ----
    float4 xv[2][4];
    {
        const int d4 = q * 2;
        xv[0][0] = xr0_g0[d4]; xv[0][1] = xr0_g0[d4 + 1];
        xv[0][2] = xr1_g0[d4]; xv[0][3] = xr1_g0[d4 + 1];
    }

    // ---- stage B image (already padded+converted), -musq/2, prec ----
    {
        const bf16x8* src = (const bf16x8*)Bp;
        bf16x8* dst = (bf16x8*)sB;
        #pragma unroll
        for (int i = 0; i < B_CHUNKS / 256; ++i)   // 17 iterations
            dst[i * 256 + tid] = src[i * 256 + tid];
        sMusq[tid] = -musqg[tid];
        if (tid < D_DIM) sPrec[tid] = prec[tid];
    }
    __syncthreads();

    float lacc = 0.f;    // accumulates 0.5*xs - lse (per-lane partial)

    #pragma unroll
    for (int rg = 0; rg < 2; ++rg) {
        const float4* xr0 = (rg == 0) ? xr0_g0 : xr0_g1;
        const float4* xr1 = (rg == 0) ? xr1_g0 : xr1_g1;

        // ---- acc init = -0.5*musq[col] (bias folded into C operand) ----
        f32x4 acc[2][16];
        #pragma unroll
        for (int c = 0; c < 16; ++c) {
            float mneg = sMusq[c * 16 + low4];
            #pragma unroll
            for (int i = 0; i < 4; ++i) { acc[0][c][i] = mneg; acc[1][c][i] = mneg; }
        }

        float xsA = 0.f, xsB = 0.f;

        #pragma unroll
        for (int k = 0; k < 4; ++k) {
            float4* cur = xv[k & 1];
            float4* nxt = xv[(k + 1) & 1];
            // prefetch next k-slice (or next rowgroup's k0) before consuming cur
            if (k < 3) {
                const int d4 = (k + 1) * 8 + q * 2;
                nxt[0] = xr0[d4]; nxt[1] = xr0[d4 + 1];
                nxt[2] = xr1[d4]; nxt[3] = xr1[d4 + 1];
            } else if (rg == 0) {
                const int d4 = q * 2;
                nxt[0] = xr0_g1[d4]; nxt[1] = xr0_g1[d4 + 1];
                nxt[2] = xr1_g1[d4]; nxt[3] = xr1_g1[d4 + 1];
            }

            const int d4 = k * 8 + q * 2;
            float4 pa = *(const float4*)&sPrec[d4 * 4];       // broadcast LDS read
            float4 pb = *(const float4*)&sPrec[d4 * 4 + 4];

            xsA += pa.x*cur[0].x*cur[0].x + pa.y*cur[0].y*cur[0].y
                 + pa.z*cur[0].z*cur[0].z + pa.w*cur[0].w*cur[0].w;
            xsB += pb.x*cur[1].x*cur[1].x + pb.y*cur[1].y*cur[1].y
                 + pb.z*cur[1].z*cur[1].z + pb.w*cur[1].w*cur[1].w;
            xsA += pa.x*cur[2].x*cur[2].x + pa.y*cur[2].y*cur[2].y
                 + pa.z*cur[2].z*cur[2].z + pa.w*cur[2].w*cur[2].w;
            xsB += pb.x*cur[3].x*cur[3].x + pb.y*cur[3].y*cur[3].y
                 + pb.z*cur[3].z*cur[3].z + pb.w*cur[3].w*cur[3].w;

            bf16x8 a0 = pack8(cur[0], cur[1]);
            bf16x8 a1 = pack8(cur[2], cur[3]);

            #pragma unroll
            for (int c = 0; c < 16; ++c) {
                const unsigned short* bp =
                    &sB[(c * 16 + low4) * LDSB_STRIDE + k * 32 + q * 8];
                bf16x8 b = *(const bf16x8*)bp;   // ds_read_b128, 16B aligned
                acc[0][c] = __builtin_amdgcn_mfma_f32_16x16x32_bf16(a0, b, acc[0][c], 0, 0, 0);
                acc[1][c] = __builtin_amdgcn_mfma_f32_16x16x32_bf16(a1, b, acc[1][c], 0, 0, 0);
            }
        }

        // ---- epilogue: per-row logsumexp (acc already = cross - 0.5*musq) ----
        float lsum = 0.f;
        #pragma unroll
        for (int m = 0; m < 2; ++m) {
            #pragma unroll
            for (int i = 0; i < 4; ++i) {
                float vmax = -1e30f;
                #pragma unroll
                for (int c = 0; c < 16; ++c) vmax = fmaxf(vmax, acc[m][c][i]);
                vmax = fmaxf(vmax, __shfl_xor(vmax, 1));
                vmax = fmaxf(vmax, __shfl_xor(vmax, 2));
                vmax = fmaxf(vmax, __shfl_xor(vmax, 4));
                vmax = fmaxf(vmax, __shfl_xor(vmax, 8));
                float s = 0.f;
                #pragma unroll
                for (int c = 0; c < 16; ++c) s += __expf(acc[m][c][i] - vmax);
                s += __shfl_xor(s, 1); s += __shfl_xor(s, 2);
                s += __shfl_xor(s, 4); s += __shfl_xor(s, 8);
                if (low4 == 0) lsum += vmax + __logf(s);
            }
        }
        lacc += 0.5f * (xsA + xsB) - lsum;
    }

    // ---- block reduction, one atomic ----
    lacc += __shfl_xor(lacc, 32); lacc += __shfl_xor(lacc, 16);
    lacc += __shfl_xor(lacc, 8);  lacc += __shfl_xor(lacc, 4);
    lacc += __shfl_xor(lacc, 2);  lacc += __shfl_xor(lacc, 1);
    if (lane == 0) sRed[wave] = lacc;
    __syncthreads();
    if (tid == 0) atomicAdd(out, sRed[0] + sRed[1] + sRed[2] + sRed[3]);
}

extern "C" void kernel_launch(void* const* d_in, const int* in_sizes, int n_in,
                              void* d_out, int out_size, void* d_ws, size_t ws_size,
                              hipStream_t stream) {
    const float* x    = (const float*)d_in[0];
    const float* mu   = (const float*)d_in[1];
    const float* prec = (const float*)d_in[2];
    float* out = (float*)d_out;

    unsigned short* Bp = (unsigned short*)d_ws;                      // 69632 B
    float* musq = (float*)((char*)d_ws + K_MIX * LDSB_STRIDE * 2);   // +1024 B

    hipMemsetAsync(d_out, 0, sizeof(float), stream);
    prep_kernel<<<32, 256, 0, stream>>>(mu, prec, Bp, musq);
    mixture_main<<<N_ROWS / 256, 256, 0, stream>>>(x, Bp, musq, prec, out);
}

// Round 4
// 112.025 us; speedup vs baseline: 2.0446x; 2.0446x over previous
//
#include <hip/hip_runtime.h>
#include <hip/hip_bf16.h>

#define N_ROWS 131072
#define K_MIX  256
#define D_DIM  128
#define LDSB_STRIDE 136            // shorts per B row: 128 + 8 pad (rows 272 B, 16B aligned)
#define B_CHUNKS (K_MIX * LDSB_STRIDE / 8)   // 4352 bf16x8 chunks = 69632 B

typedef float  f32x4  __attribute__((ext_vector_type(4)));
typedef short  bf16x8 __attribute__((ext_vector_type(8)));

__device__ inline bf16x8 pack8(float4 a, float4 b) {
    union { bf16x8 v; __hip_bfloat162 h[4]; } u;
    u.h[0] = __float22bfloat162_rn(make_float2(a.x, a.y));
    u.h[1] = __float22bfloat162_rn(make_float2(a.z, a.w));
    u.h[2] = __float22bfloat162_rn(make_float2(b.x, b.y));
    u.h[3] = __float22bfloat162_rn(make_float2(b.z, b.w));
    return u.v;
}

// ---------------- prep: ws <- padded bf16(prec*mu), fp32 0.5*musq ----------------
__global__ void prep_kernel(const float* __restrict__ mu,
                            const float* __restrict__ prec,
                            unsigned short* __restrict__ Bp,
                            float* __restrict__ musq)
{
    int idx = blockIdx.x * 256 + threadIdx.x;   // 0..8191 float4s of mu
    int row = idx >> 5;                          // mixture component k
    int c4  = idx & 31;                          // float4 within row
    float4 mv = ((const float4*)mu)[idx];
    float4 pv = ((const float4*)prec)[c4];
    float px = mv.x * pv.x, py = mv.y * pv.y, pz = mv.z * pv.z, pw = mv.w * pv.w;
    union { ushort4 u4; __hip_bfloat162 h[2]; } h;
    h.h[0] = __float22bfloat162_rn(make_float2(px, py));
    h.h[1] = __float22bfloat162_rn(make_float2(pz, pw));
    *(ushort4*)&Bp[row * LDSB_STRIDE + c4 * 4] = h.u4;
    if (c4 == 31) {     // zero the 8-short pad
        bf16x8 z = (bf16x8)0;
        *(bf16x8*)&Bp[row * LDSB_STRIDE + 128] = z;
    }
    float ps = px * mv.x + py * mv.y + pz * mv.z + pw * mv.w;
    ps += __shfl_xor(ps, 1);  ps += __shfl_xor(ps, 2);
    ps += __shfl_xor(ps, 4);  ps += __shfl_xor(ps, 8);
    ps += __shfl_xor(ps, 16);
    if ((threadIdx.x & 31) == 0) musq[row] = 0.5f * ps;   // pre-scaled
}

// ---------------- main ----------------
__global__ __launch_bounds__(256, 2)
void mixture_main(const float* __restrict__ x,
                  const unsigned short* __restrict__ Bp,
                  const float* __restrict__ musqg,
                  const float* __restrict__ prec,
                  float* __restrict__ out)
{
    __shared__ __align__(16) unsigned short sB[K_MIX * LDSB_STRIDE];
    __shared__ float sMusq[K_MIX];      // holds -0.5*musq (acc-init ready)
    __shared__ float sPrec[D_DIM];
    __shared__ float sRed[4];

    const int tid  = threadIdx.x;
    const int lane = tid & 63;
    const int wave = tid >> 6;
    const int low4 = lane & 15;
    const int q    = lane >> 4;

    // ---- stage B image (already padded+converted), -musq/2, prec ----
    {
        const bf16x8* src = (const bf16x8*)Bp;
        bf16x8* dst = (bf16x8*)sB;
        #pragma unroll
        for (int i = 0; i < B_CHUNKS / 256; ++i)   // 17 iterations
            dst[i * 256 + tid] = src[i * 256 + tid];
        sMusq[tid] = -musqg[tid];
        if (tid < D_DIM) sPrec[tid] = prec[tid];
    }
    __syncthreads();

    const float4* x4 = (const float4*)x;
    const int rbase = blockIdx.x * 256 + wave * 32;
    const float4* xr0 = x4 + (size_t)(rbase + low4) * 32;
    const float4* xr1 = x4 + (size_t)(rbase + low4 + 16) * 32;

    float lacc = 0.f;    // per-lane partial of (0.5*xsq - lse)

    #pragma unroll 1
    for (int rg = 0; rg < 2; ++rg) {
        const float4* p0 = xr0 + rg * 128 * 32;
        const float4* p1 = xr1 + rg * 128 * 32;

        // ---- phase 1: load this rowgroup's x (16 independent float4) ----
        float4 xv[4][4];
        #pragma unroll
        for (int k = 0; k < 4; ++k) {
            const int d4 = k * 8 + q * 2;
            xv[k][0] = p0[d4]; xv[k][1] = p0[d4 + 1];
            xv[k][2] = p1[d4]; xv[k][3] = p1[d4 + 1];
        }

        // ---- phase 2: xsq partials + pack A-fragments (xv dies here) ----
        float xsA = 0.f, xsB = 0.f;
        bf16x8 a0[4], a1[4];
        #pragma unroll
        for (int k = 0; k < 4; ++k) {
            const int d4 = k * 8 + q * 2;
            float4 pa = *(const float4*)&sPrec[d4 * 4];
            float4 pb = *(const float4*)&sPrec[d4 * 4 + 4];
            xsA += pa.x*xv[k][0].x*xv[k][0].x + pa.y*xv[k][0].y*xv[k][0].y
                 + pa.z*xv[k][0].z*xv[k][0].z + pa.w*xv[k][0].w*xv[k][0].w;
            xsB += pb.x*xv[k][1].x*xv[k][1].x + pb.y*xv[k][1].y*xv[k][1].y
                 + pb.z*xv[k][1].z*xv[k][1].z + pb.w*xv[k][1].w*xv[k][1].w;
            xsA += pa.x*xv[k][2].x*xv[k][2].x + pa.y*xv[k][2].y*xv[k][2].y
                 + pa.z*xv[k][2].z*xv[k][2].z + pa.w*xv[k][2].w*xv[k][2].w;
            xsB += pb.x*xv[k][3].x*xv[k][3].x + pb.y*xv[k][3].y*xv[k][3].y
                 + pb.z*xv[k][3].z*xv[k][3].z + pb.w*xv[k][3].w*xv[k][3].w;
            a0[k] = pack8(xv[k][0], xv[k][1]);
            a1[k] = pack8(xv[k][2], xv[k][3]);
        }

        // per-lane online-LSE state: rows r = rg*128 + m*16 + q*4 + i
        float m_run[2][4], s_run[2][4];
        #pragma unroll
        for (int m = 0; m < 2; ++m)
            #pragma unroll
            for (int i = 0; i < 4; ++i) { m_run[m][i] = -3.0e38f; s_run[m][i] = 0.f; }

        // ---- phases 3/4: two column halves of 8 c-frags each ----
        #pragma unroll 1
        for (int h = 0; h < 2; ++h) {
            f32x4 acc[2][8];
            #pragma unroll
            for (int c = 0; c < 8; ++c) {
                float mneg = sMusq[(h * 8 + c) * 16 + low4];   // = -0.5*musq[col]
                #pragma unroll
                for (int i = 0; i < 4; ++i) { acc[0][c][i] = mneg; acc[1][c][i] = mneg; }
            }

            #pragma unroll
            for (int k = 0; k < 4; ++k) {
                #pragma unroll
                for (int c = 0; c < 8; ++c) {
                    const unsigned short* bp =
                        &sB[((h * 8 + c) * 16 + low4) * LDSB_STRIDE + k * 32 + q * 8];
                    bf16x8 b = *(const bf16x8*)bp;   // ds_read_b128
                    acc[0][c] = __builtin_amdgcn_mfma_f32_16x16x32_bf16(a0[k], b, acc[0][c], 0, 0, 0);
                    acc[1][c] = __builtin_amdgcn_mfma_f32_16x16x32_bf16(a1[k], b, acc[1][c], 0, 0, 0);
                }
            }

            // fold this half into running (m,s) — acc registers die here
            #pragma unroll
            for (int m = 0; m < 2; ++m) {
                #pragma unroll
                for (int i = 0; i < 4; ++i) {
                    float v0 = acc[m][0][i], v1 = acc[m][1][i];
                    float v2 = acc[m][2][i], v3 = acc[m][3][i];
                    float v4 = acc[m][4][i], v5 = acc[m][5][i];
                    float v6 = acc[m][6][i], v7 = acc[m][7][i];
                    float hmax = fmaxf(fmaxf(fmaxf(v0, v1), fmaxf(v2, v3)),
                                       fmaxf(fmaxf(v4, v5), fmaxf(v6, v7)));
                    float hsum = __expf(v0 - hmax) + __expf(v1 - hmax)
                               + __expf(v2 - hmax) + __expf(v3 - hmax)
                               + __expf(v4 - hmax) + __expf(v5 - hmax)
                               + __expf(v6 - hmax) + __expf(v7 - hmax);
                    float mr = m_run[m][i];
                    float mn = fmaxf(mr, hmax);
                    s_run[m][i] = s_run[m][i] * __expf(mr - mn) + hsum * __expf(hmax - mn);
                    m_run[m][i] = mn;
                }
            }
        }

        // ---- phase 5: merge (m,s) across the 16 col-lanes, accumulate ----
        #pragma unroll
        for (int m = 0; m < 2; ++m) {
            #pragma unroll
            for (int i = 0; i < 4; ++i) {
                float mr = m_run[m][i], sr = s_run[m][i];
                #pragma unroll
                for (int step = 1; step <= 8; step <<= 1) {
                    float mo = __shfl_xor(mr, step);
                    float so = __shfl_xor(sr, step);
                    float mn = fmaxf(mr, mo);
                    sr = sr * __expf(mr - mn) + so * __expf(mo - mn);
                    mr = mn;
                }
                if (low4 == 0) lacc -= mr + __logf(sr);
            }
        }
        lacc += 0.5f * (xsA + xsB);
    }

    // ---- block reduction, one atomic ----
    lacc += __shfl_xor(lacc, 32); lacc += __shfl_xor(lacc, 16);
    lacc += __shfl_xor(lacc, 8);  lacc += __shfl_xor(lacc, 4);
    lacc += __shfl_xor(lacc, 2);  lacc += __shfl_xor(lacc, 1);
    if (lane == 0) sRed[wave] = lacc;
    __syncthreads();
    if (tid == 0) atomicAdd(out, sRed[0] + sRed[1] + sRed[2] + sRed[3]);
}

extern "C" void kernel_launch(void* const* d_in, const int* in_sizes, int n_in,
                              void* d_out, int out_size, void* d_ws, size_t ws_size,
                              hipStream_t stream) {
    const float* x    = (const float*)d_in[0];
    const float* mu   = (const float*)d_in[1];
    const float* prec = (const float*)d_in[2];
    float* out = (float*)d_out;

    unsigned short* Bp = (unsigned short*)d_ws;                      // 69632 B
    float* musq = (float*)((char*)d_ws + K_MIX * LDSB_STRIDE * 2);   // +1024 B

    hipMemsetAsync(d_out, 0, sizeof(float), stream);
    prep_kernel<<<32, 256, 0, stream>>>(mu, prec, Bp, musq);
    mixture_main<<<N_ROWS / 256, 256, 0, stream>>>(x, Bp, musq, prec, out);
}